// Round 6
// baseline (851.875 us; speedup 1.0000x reference)
//
#include <hip/hip_runtime.h>
#include <cstddef>

#define NN 512
#define DD 384
#define EE 128
#define HH 8
#define JSPLIT 16          // j-splits in fused attention (32 j each)

static constexpr float SCAL_SCALE  = 0.1443375673f;   // 1/sqrt(3*16)
static constexpr float POINT_SCALE = 0.1360827635f;   // 1/sqrt(3*4*4.5)
static constexpr float PAIR_SCALE  = 0.5773502692f;   // 1/sqrt(3)
static constexpr float LN_EPS = 1e-5f;
static constexpr float EPS    = 1e-8f;

typedef __bf16 bf16x8 __attribute__((ext_vector_type(8)));
typedef float  f32x4  __attribute__((ext_vector_type(4)));

__device__ __forceinline__ unsigned short bf16_bits(float v) {
    union { __bf16 b; unsigned short s; } c; c.b = (__bf16)v; return c.s;
}
__device__ __forceinline__ float bits2f(unsigned u) {
    union { unsigned u; float f; } c; c.u = u; return c.f;
}

// ---------------------------------------------------------------------------
// Unified prep: fp32 W[K][N] -> bf16 Wt[N][K] for all weights (proj combined
// into WprojT[672][384]) + straight fp32->bf16 copy of nf -> nfb.
// ---------------------------------------------------------------------------
__global__ __launch_bounds__(256) void prep_weights_kernel(
    const float* __restrict__ Wo, const float* __restrict__ W1,
    const float* __restrict__ W2, const float* __restrict__ W3,
    const float* __restrict__ Wq_s, const float* __restrict__ Wk_s,
    const float* __restrict__ Wv_s,
    const float* __restrict__ Wq_p, const float* __restrict__ Wk_p,
    const float* __restrict__ Wv_p, const float* __restrict__ nf,
    unsigned short* __restrict__ WoT, unsigned short* __restrict__ W1T,
    unsigned short* __restrict__ W2T, unsigned short* __restrict__ W3T,
    unsigned short* __restrict__ WprojT, unsigned short* __restrict__ nfb)
{
    const int b = blockIdx.x;
    if (b >= 1884) {   // nf convert: 192 blocks x 1024 elems
        const int idx = (b - 1884) * 1024 + threadIdx.x * 4;
        float4 v = *(const float4*)(nf + idx);
        unsigned lo = bf16_bits(v.x) | ((unsigned)bf16_bits(v.y) << 16);
        unsigned hi = bf16_bits(v.z) | ((unsigned)bf16_bits(v.w) << 16);
        uint2 pk; pk.x = lo; pk.y = hi;
        *(uint2*)(nfb + idx) = pk;
        return;
    }
    const float* W; unsigned short* out;
    int K, N, tile, rowoff = 0;
    if (b < 480)       { W = Wo;   out = WoT;    K = 1280; N = 384; tile = b; }
    else if (b < 768)  { W = W1;   out = W1T;    K = 384;  N = 768; tile = b - 480; }
    else if (b < 1344) { W = W2;   out = W2T;    K = 768;  N = 768; tile = b - 768; }
    else if (b < 1632) { W = W3;   out = W3T;    K = 768;  N = 384; tile = b - 1344; }
    else if (b < 1680) { W = Wq_s; out = WprojT; K = 384;  N = 128; tile = b - 1632; rowoff = 0; }
    else if (b < 1728) { W = Wk_s; out = WprojT; K = 384;  N = 128; tile = b - 1680; rowoff = 128; }
    else if (b < 1776) { W = Wv_s; out = WprojT; K = 384;  N = 128; tile = b - 1728; rowoff = 256; }
    else if (b < 1812) { W = Wq_p; out = WprojT; K = 384;  N = 96;  tile = b - 1776; rowoff = 384; }
    else if (b < 1848) { W = Wk_p; out = WprojT; K = 384;  N = 96;  tile = b - 1812; rowoff = 480; }
    else               { W = Wv_p; out = WprojT; K = 384;  N = 96;  tile = b - 1848; rowoff = 576; }

    const int ntn = N / 32;
    const int n0 = (tile % ntn) * 32, k0 = (tile / ntn) * 32;
    __shared__ float tb[32][33];
    const int tx = threadIdx.x & 31, ty = threadIdx.x >> 5;
    #pragma unroll
    for (int dy = 0; dy < 32; dy += 8)
        tb[ty + dy][tx] = W[(size_t)(k0 + ty + dy) * N + n0 + tx];
    __syncthreads();
    #pragma unroll
    for (int dy = 0; dy < 32; dy += 8)
        out[(size_t)(rowoff + n0 + ty + dy) * K + k0 + tx] = bf16_bits(tb[tx][ty + dy]);
}

// ---------------------------------------------------------------------------
// Barrier-free bf16 GEMM: Y[M,NOUT] = Xb[M,K](bf16) @ Wt[NOUT,K]^T + bias.
// Per-wave direct-global A/B fragment loads, no LDS. Block: 64m x 16n.
// grid (NOUT/16, M/64).
// ---------------------------------------------------------------------------
template <int K, int NOUT, bool RELU, bool HASB, bool OUTBF>
__global__ __launch_bounds__(256) void gemm_bf16(
    const unsigned short* __restrict__ Xb, const unsigned short* __restrict__ Wt,
    const float* __restrict__ bias, void* __restrict__ Yv)
{
    const int t = threadIdx.x;
    const int w = t >> 6, lane = t & 63;
    const int r = lane & 15, q = lane >> 4;
    const int n0 = blockIdx.x * 16;
    const int m0 = blockIdx.y * 64 + w * 16;

    const unsigned short* xrow = Xb + (size_t)(m0 + r) * K + q * 8;
    const unsigned short* wrow = Wt + (size_t)(n0 + r) * K + q * 8;

    f32x4 acc = {0.f, 0.f, 0.f, 0.f};
    #pragma unroll 4
    for (int k0 = 0; k0 < K; k0 += 32) {
        union { uint4 u; bf16x8 v; } au, bu;
        au.u = *(const uint4*)(xrow + k0);
        bu.u = *(const uint4*)(wrow + k0);
        acc = __builtin_amdgcn_mfma_f32_16x16x32_bf16(au.v, bu.v, acc, 0, 0, 0);
    }
    const int n = n0 + r;
    const float bi = HASB ? bias[n] : 0.f;
    #pragma unroll
    for (int reg = 0; reg < 4; reg++) {
        const int m = m0 + q * 4 + reg;
        float v = acc[reg] + bi;
        if (RELU) v = fmaxf(v, 0.f);
        if (OUTBF) ((unsigned short*)Yv)[(size_t)m * NOUT + n] = bf16_bits(v);
        else       ((float*)Yv)[(size_t)m * NOUT + n] = v;
    }
}

// ---------------------------------------------------------------------------
// Post-projection: rigid transform + pack Q'/K'/svT from proj_out[i][672].
// ---------------------------------------------------------------------------
__global__ __launch_bounds__(256) void ipa_post_kernel(
    const float* __restrict__ proj_out, const float* __restrict__ rot,
    const float* __restrict__ trans, const float* __restrict__ pw,
    const float* __restrict__ bb,
    unsigned short* __restrict__ Qp, unsigned short* __restrict__ Kp,
    unsigned short* __restrict__ svT)
{
    const int i = blockIdx.x;
    const int t = threadIdx.x;
    __shared__ float outs[672];
    __shared__ float ptg[288];
    __shared__ float q2s[8], k2s[8], pwh[8];

    for (int f = t; f < 672; f += 256) outs[f] = proj_out[(size_t)i * 672 + f];
    if (t < 8) pwh[t] = 0.5f * POINT_SCALE * log1pf(expf(pw[t]));
    __syncthreads();

    for (int f = t; f < 288; f += 256) {
        int which = f / 96, idx = f % 96;
        int hd = idx / 3, r = idx % 3;
        float acc = trans[(size_t)i * 3 + r];
        #pragma unroll
        for (int c = 0; c < 3; c++)
            acc += outs[384 + which * 96 + hd * 3 + c] * rot[(size_t)i * 9 + c * 3 + r];
        ptg[f] = acc;
    }
    __syncthreads();
    if (t < 16) {
        int which = t / 8, h = t % 8;
        float acc = 0.f;
        #pragma unroll
        for (int m = 0; m < 12; m++) {
            float v = ptg[which * 96 + h * 12 + m];
            acc += v * v;
        }
        (which ? k2s : q2s)[h] = acc;
    }
    __syncthreads();

    {
        const int h = t >> 5, d = t & 31;
        float qv, kv;
        if (d < 16)      { qv = outs[h * 16 + d] * SCAL_SCALE; kv = outs[128 + h * 16 + d]; }
        else if (d < 28) { qv = ptg[h * 12 + d - 16] * (2.f * pwh[h]); kv = ptg[96 + h * 12 + d - 16]; }
        else if (d == 28){ qv = -pwh[h] * q2s[h]; kv = 1.f; }
        else if (d == 29){ qv = 1.f; kv = -pwh[h] * k2s[h]; }
        else if (d == 30){ qv = 1.f; kv = bb[h] * PAIR_SCALE; }
        else             { qv = 0.f; kv = 0.f; }
        Qp[((size_t)i * 8 + h) * 32 + d] = bf16_bits(qv);
        Kp[((size_t)i * 8 + h) * 32 + d] = bf16_bits(kv);
    }
    if (t < 128) {
        int h = t >> 4, v = t & 15;
        svT[((size_t)h * 32 + v) * NN + i] = bf16_bits(outs[256 + h * 16 + v]);
    } else if (t < 224) {
        int idx = t - 128, h = idx / 12, m = idx % 12;
        svT[((size_t)h * 32 + 16 + m) * NN + i] = bf16_bits(ptg[192 + idx]);
    }
}

// ---------------------------------------------------------------------------
// FUSED flash-IPA v2. Block: 8 i-rows x 32 j (4 subtiles of 8 j).
// grid (16 j-splits, 64 i-tiles) = 1024 blocks. qk logits hoisted to Lqk once
// per block; edge prefetched into registers across phases; accumulate thread
// map (i, h, e-part) with uint4 LDS reads.
// ---------------------------------------------------------------------------
__global__ __launch_bounds__(256, 3) void ipa_fused2(
    const float* __restrict__ edge,
    const unsigned short* __restrict__ Qp, const unsigned short* __restrict__ Kp,
    const unsigned short* __restrict__ svT, const float* __restrict__ Wb,
    float* __restrict__ Opart, float* __restrict__ Mpart, float* __restrict__ Lpart)
{
    const int js = blockIdx.x;           // 0..15
    const int it = blockIdx.y;           // 0..63
    const int i0 = it * 8;
    const int jbase = js * 32;
    const int t = threadIdx.x;
    const int w = t >> 6, lane = t & 63;
    const int r = lane & 15, q = lane >> 4;

    __shared__ unsigned short wbT[16 * 128];   // [h(16)][e] *PAIR_SCALE
    __shared__ unsigned short edA[64 * 128];   // [row=jl*8+il][e] chunk^(row&15)
    __shared__ float Lqk[64 * 37];             // [(h*8+i)][j(32) pad37]
    __shared__ float Lb[64 * 9];               // [(h*8+i)][j(8) pad9]
    __shared__ unsigned short svj[8 * 8 * 32]; // [h][j][c pad32]
    __shared__ float mrow[64], lrow[64], arow[64];

    for (int idx = t; idx < 2048; idx += 256) {
        int h = idx >> 7, e = idx & 127;
        wbT[idx] = bf16_bits((h < 8) ? Wb[e * 8 + h] * PAIR_SCALE : 0.f);
    }
    if (t < 64) { mrow[t] = -1e30f; lrow[t] = 0.f; }
    __syncthreads();

    bf16x8 wbf[4];
    #pragma unroll
    for (int s = 0; s < 4; s++)
        wbf[s] = *(const bf16x8*)&wbT[r * 128 + s * 32 + q * 8];

    // qk logits for the whole 32-j strip, once: wave w owns h = 2w, 2w+1
    #pragma unroll
    for (int hh = 0; hh < 2; hh++) {
        const int h = w * 2 + hh;
        bf16x8 aq = *(const bf16x8*)&Qp[((size_t)(i0 + (r & 7)) * 8 + h) * 32 + q * 8];
        #pragma unroll
        for (int jt = 0; jt < 2; jt++) {
            bf16x8 bk = *(const bf16x8*)&Kp[((size_t)(jbase + jt * 16 + r) * 8 + h) * 32 + q * 8];
            f32x4 acc = {0.f, 0.f, 0.f, 0.f};
            acc = __builtin_amdgcn_mfma_f32_16x16x32_bf16(aq, bk, acc, 0, 0, 0);
            if (q < 2) {
                #pragma unroll
                for (int reg = 0; reg < 4; reg++)
                    Lqk[(h * 8 + q * 4 + reg) * 37 + jt * 16 + r] = acc[reg];
            }
        }
    }

    // prefetch machinery
    const int sj = t >> 5, sih = (t >> 4) & 1, sseg = t & 15;
    const int hsv = t / 28, csv = t % 28;    // valid t<224
    float4 pf[8];
    uint4 svpf;
    {
        const int j0 = jbase;
        #pragma unroll
        for (int il = 0; il < 4; il++) {
            const float* src = edge + (((size_t)(i0 + sih * 4 + il) * NN) + (j0 + sj)) * EE + sseg * 8;
            pf[il * 2]     = *(const float4*)src;
            pf[il * 2 + 1] = *(const float4*)(src + 4);
        }
        if (t < 224) svpf = *(const uint4*)&svT[(size_t)(hsv * 32 + csv) * NN + j0];
    }

    // accumulators: thread = (i = t>>5, h = (t>>2)&7, part = t&3)
    const int ai = t >> 5, ah = (t >> 2) & 7, ap = t & 3;
    const int prow = ah * 8 + ai;
    float rp[32];
    float sva[8];
    #pragma unroll
    for (int z = 0; z < 32; z++) rp[z] = 0.f;
    #pragma unroll
    for (int s = 0; s < 8; s++) sva[s] = 0.f;

    for (int st = 0; st < 4; st++) {
        __syncthreads();   // edA/svj free
        // commit prefetched tile to LDS
        #pragma unroll
        for (int il = 0; il < 4; il++) {
            const int row = sj * 8 + sih * 4 + il;
            union { bf16x8 v; uint4 u; } pk;
            pk.v[0] = (__bf16)pf[il*2].x;   pk.v[1] = (__bf16)pf[il*2].y;
            pk.v[2] = (__bf16)pf[il*2].z;   pk.v[3] = (__bf16)pf[il*2].w;
            pk.v[4] = (__bf16)pf[il*2+1].x; pk.v[5] = (__bf16)pf[il*2+1].y;
            pk.v[6] = (__bf16)pf[il*2+1].z; pk.v[7] = (__bf16)pf[il*2+1].w;
            *(uint4*)&edA[row * 128 + ((sseg ^ (row & 15)) * 8)] = pk.u;
        }
        if (t < 224) {
            svj[(hsv * 8 + 0) * 32 + csv] = (unsigned short)(svpf.x & 0xffff);
            svj[(hsv * 8 + 1) * 32 + csv] = (unsigned short)(svpf.x >> 16);
            svj[(hsv * 8 + 2) * 32 + csv] = (unsigned short)(svpf.y & 0xffff);
            svj[(hsv * 8 + 3) * 32 + csv] = (unsigned short)(svpf.y >> 16);
            svj[(hsv * 8 + 4) * 32 + csv] = (unsigned short)(svpf.z & 0xffff);
            svj[(hsv * 8 + 5) * 32 + csv] = (unsigned short)(svpf.z >> 16);
            svj[(hsv * 8 + 6) * 32 + csv] = (unsigned short)(svpf.w & 0xffff);
            svj[(hsv * 8 + 7) * 32 + csv] = (unsigned short)(svpf.w >> 16);
        }
        // issue next prefetch (overlaps MFMA + softmax + accumulate)
        if (st < 3) {
            const int j0 = jbase + (st + 1) * 8;
            #pragma unroll
            for (int il = 0; il < 4; il++) {
                const float* src = edge + (((size_t)(i0 + sih * 4 + il) * NN) + (j0 + sj)) * EE + sseg * 8;
                pf[il * 2]     = *(const float4*)src;
                pf[il * 2 + 1] = *(const float4*)(src + 4);
            }
            if (t < 224) svpf = *(const uint4*)&svT[(size_t)(hsv * 32 + csv) * NN + j0];
        }
        __syncthreads();

        // pair-bias MFMA: wave w covers rows w*16..w*16+15 = (jl,il) pairs
        {
            f32x4 acc = {0.f, 0.f, 0.f, 0.f};
            #pragma unroll
            for (int s = 0; s < 4; s++) {
                bf16x8 a = *(const bf16x8*)&edA[(w * 16 + r) * 128 + (((s * 4 + q) ^ r) * 8)];
                acc = __builtin_amdgcn_mfma_f32_16x16x32_bf16(a, wbf[s], acc, 0, 0, 0);
            }
            if (r < 8) {   // col r = h; row m = q*4+reg -> jl = w*2+(m>>3), il = m&7
                #pragma unroll
                for (int reg = 0; reg < 4; reg++) {
                    const int m = q * 4 + reg;
                    Lb[(r * 8 + (m & 7)) * 9 + (w * 2 + (m >> 3))] = acc[reg];
                }
            }
        }
        __syncthreads();

        // online softmax: t<64 owns (h = t>>3, i = t&7)
        if (t < 64) {
            float lg[8];
            float mx = -1e30f;
            #pragma unroll
            for (int j = 0; j < 8; j++) {
                lg[j] = Lb[t * 9 + j] + Lqk[t * 37 + st * 8 + j];
                mx = fmaxf(mx, lg[j]);
            }
            const float mnew = fmaxf(mrow[t], mx);
            const float al = __expf(mrow[t] - mnew);
            float sum = 0.f;
            #pragma unroll
            for (int j = 0; j < 8; j++) {
                float p = __expf(lg[j] - mnew);
                Lb[t * 9 + j] = p;
                sum += p;
            }
            lrow[t] = lrow[t] * al + sum;
            mrow[t] = mnew;
            arow[t] = al;
        }
        __syncthreads();

        // accumulate
        const float al = arow[prow];
        float pj[8];
        #pragma unroll
        for (int j = 0; j < 8; j++) pj[j] = Lb[prow * 9 + j];
        #pragma unroll
        for (int z = 0; z < 32; z++) rp[z] *= al;
        #pragma unroll
        for (int s = 0; s < 8; s++) sva[s] *= al;

        #pragma unroll
        for (int j = 0; j < 8; j++) {
            const int row = j * 8 + ai;
            const float p = pj[j];
            #pragma unroll
            for (int u = 0; u < 4; u++) {
                uint4 ev = *(const uint4*)&edA[row * 128 + (((ap * 4 + u) ^ (row & 15)) * 8)];
                rp[u*8+0] += p * bits2f(ev.x << 16);
                rp[u*8+1] += p * bits2f(ev.x & 0xffff0000u);
                rp[u*8+2] += p * bits2f(ev.y << 16);
                rp[u*8+3] += p * bits2f(ev.y & 0xffff0000u);
                rp[u*8+4] += p * bits2f(ev.z << 16);
                rp[u*8+5] += p * bits2f(ev.z & 0xffff0000u);
                rp[u*8+6] += p * bits2f(ev.w << 16);
                rp[u*8+7] += p * bits2f(ev.w & 0xffff0000u);
            }
            uint4 sv = *(const uint4*)&svj[(ah * 8 + j) * 32 + ap * 8];
            sva[0] += p * bits2f(sv.x << 16);
            sva[1] += p * bits2f(sv.x & 0xffff0000u);
            sva[2] += p * bits2f(sv.y << 16);
            sva[3] += p * bits2f(sv.y & 0xffff0000u);
            sva[4] += p * bits2f(sv.z << 16);
            sva[5] += p * bits2f(sv.z & 0xffff0000u);
            sva[6] += p * bits2f(sv.w << 16);
            sva[7] += p * bits2f(sv.w & 0xffff0000u);
        }
    }

    // writeout partials (all float4-aligned)
    float* orow = Opart + (size_t)((js * 64 + it) * 8 + ai) * 1248;
    #pragma unroll
    for (int u = 0; u < 8; u++) {
        f32x4 vv = {rp[u*4+0], rp[u*4+1], rp[u*4+2], rp[u*4+3]};
        *(f32x4*)&orow[ah * 156 + 28 + ap * 32 + u * 4] = vv;
    }
    {
        f32x4 v0 = {sva[0], sva[1], sva[2], sva[3]};
        if (ap < 3) {
            f32x4 v1 = {sva[4], sva[5], sva[6], sva[7]};
            *(f32x4*)&orow[ah * 156 + ap * 8]     = v0;
            *(f32x4*)&orow[ah * 156 + ap * 8 + 4] = v1;
        } else {
            *(f32x4*)&orow[ah * 156 + 24] = v0;   // c 24..27
        }
    }
    if (t < 64) {
        Mpart[(size_t)(js * 64 + it) * 64 + t] = mrow[t];
        Lpart[(size_t)(js * 64 + it) * 64 + t] = lrow[t];
    }
}

// ---------------------------------------------------------------------------
// Merge partials + local frame + norms -> bf16 cat row
// [rs(128) | local(96) | norms(32) | rp(1024)]. grid 512.
// ---------------------------------------------------------------------------
__global__ __launch_bounds__(256) void ipa_merge(
    const float* __restrict__ Opart, const float* __restrict__ Mpart,
    const float* __restrict__ Lpart, const float* __restrict__ rot,
    const float* __restrict__ trans, unsigned short* __restrict__ cat_bf)
{
    const int i = blockIdx.x;
    const int itile = i >> 3, il = i & 7;
    const int t = threadIdx.x;
    __shared__ float wn[8 * JSPLIT];
    __shared__ float pts_s[96];

    if (t < 8) {
        const int h = t;
        float ms[JSPLIT], ls[JSPLIT], M = -1e30f;
        #pragma unroll
        for (int s = 0; s < JSPLIT; s++) {
            ms[s] = Mpart[(size_t)(s * 64 + itile) * 64 + h * 8 + il];
            ls[s] = Lpart[(size_t)(s * 64 + itile) * 64 + h * 8 + il];
            M = fmaxf(M, ms[s]);
        }
        float denom = 0.f, e[JSPLIT];
        #pragma unroll
        for (int s = 0; s < JSPLIT; s++) { e[s] = __expf(ms[s] - M); denom += e[s] * ls[s]; }
        const float inv = 1.f / denom;
        #pragma unroll
        for (int s = 0; s < JSPLIT; s++) wn[h * JSPLIT + s] = e[s] * inv;
    }
    __syncthreads();

    for (int col = t; col < 1248; col += 256) {
        const int h = col / 156, c = col % 156;
        float acc = 0.f;
        #pragma unroll
        for (int s = 0; s < JSPLIT; s++)
            acc += wn[h * JSPLIT + s] *
                   Opart[((size_t)(s * 64 + itile) * 8 + il) * 1248 + col];
        if (c < 16)      cat_bf[(size_t)i * 1280 + h * 16 + c] = bf16_bits(acc);
        else if (c < 28) pts_s[h * 12 + (c - 16)] = acc;
        else             cat_bf[(size_t)i * 1280 + 256 + h * 128 + (c - 28)] = bf16_bits(acc);
    }
    __syncthreads();

    const float* tr = trans + (size_t)i * 3;
    const float* R  = rot + (size_t)i * 9;
    if (t < 96) {
        int hd = t / 3, rr = t % 3;
        float acc = 0.f;
        #pragma unroll
        for (int c = 0; c < 3; c++)
            acc += (pts_s[hd * 3 + c] - tr[c]) * R[rr * 3 + c];
        cat_bf[(size_t)i * 1280 + 128 + t] = bf16_bits(acc);
    } else if (t < 128) {
        int pv = t - 96;
        float s = EPS;
        #pragma unroll
        for (int rr = 0; rr < 3; rr++) {
            float v = 0.f;
            #pragma unroll
            for (int c = 0; c < 3; c++)
                v += (pts_s[pv * 3 + c] - tr[c]) * R[rr * 3 + c];
            s += v * v;
        }
        cat_bf[(size_t)i * 1280 + 224 + pv] = bf16_bits(sqrtf(s));
    }
}

// ---------------------------------------------------------------------------
// LayerNorm per row; optional bf16 output.
// ---------------------------------------------------------------------------
template <bool OUTBF>
__global__ __launch_bounds__(256) void ln_kernel(
    const float* __restrict__ X, const float* __restrict__ g,
    const float* __restrict__ beta, void* __restrict__ Yv, int Dim)
{
    __shared__ float red[4];
    __shared__ float bc;
    const int i = blockIdx.x;
    const int t = threadIdx.x;
    const float* x = X + (size_t)i * Dim;

    float s = 0.f;
    for (int k = t; k < Dim; k += 256) s += x[k];
    #pragma unroll
    for (int off = 32; off; off >>= 1) s += __shfl_down(s, off, 64);
    if ((t & 63) == 0) red[t >> 6] = s;
    __syncthreads();
    if (t == 0) bc = red[0] + red[1] + red[2] + red[3];
    __syncthreads();
    const float mu = bc / Dim;

    float v = 0.f;
    for (int k = t; k < Dim; k += 256) { float d = x[k] - mu; v += d * d; }
    #pragma unroll
    for (int off = 32; off; off >>= 1) v += __shfl_down(v, off, 64);
    __syncthreads();
    if ((t & 63) == 0) red[t >> 6] = v;
    __syncthreads();
    if (t == 0) bc = red[0] + red[1] + red[2] + red[3];
    __syncthreads();
    const float rstd = rsqrtf(bc / Dim + LN_EPS);

    for (int k = t; k < Dim; k += 256) {
        float val = (x[k] - mu) * rstd * g[k] + beta[k];
        if (OUTBF) ((unsigned short*)Yv)[(size_t)i * Dim + k] = bf16_bits(val);
        else       ((float*)Yv)[(size_t)i * Dim + k] = val;
    }
}

// ---------------------------------------------------------------------------
extern "C" void kernel_launch(void* const* d_in, const int* in_sizes, int n_in,
                              void* d_out, int out_size, void* d_ws, size_t ws_size,
                              hipStream_t stream)
{
    const float* nf    = (const float*)d_in[0];
    const float* edge  = (const float*)d_in[1];
    const float* rot   = (const float*)d_in[2];
    const float* trans = (const float*)d_in[3];
    // d_in[4] = mask — all-True, no-op
    const float* Wq_s = (const float*)d_in[5];
    const float* Wk_s = (const float*)d_in[6];
    const float* Wv_s = (const float*)d_in[7];
    const float* Wq_p = (const float*)d_in[8];
    const float* Wk_p = (const float*)d_in[9];
    const float* Wv_p = (const float*)d_in[10];
    const float* pw   = (const float*)d_in[11];
    const float* Wb   = (const float*)d_in[12];
    const float* bb   = (const float*)d_in[13];
    const float* Wo   = (const float*)d_in[14];
    const float* bo   = (const float*)d_in[15];
    const float* g1   = (const float*)d_in[16];
    const float* be1  = (const float*)d_in[17];
    const float* W1   = (const float*)d_in[18];
    const float* b1   = (const float*)d_in[19];
    const float* W2   = (const float*)d_in[20];
    const float* b2   = (const float*)d_in[21];
    const float* W3   = (const float*)d_in[22];
    const float* b3   = (const float*)d_in[23];
    const float* g2   = (const float*)d_in[24];
    const float* be2  = (const float*)d_in[25];

    float* ws = (float*)d_ws;
    float* proj_out = ws;                    // 512*672
    float* ipa   = proj_out + 344064;        // 512*384
    float* y     = ipa + 196608;             // 512*384
    float* Opart = y + 196608;               // 16*64*8 * 1248
    float* Mpart = Opart + 10223616;         // 16*64*64
    float* Lpart = Mpart + 65536;
    unsigned short* cat_bf = (unsigned short*)(Lpart + 65536); // 512*1280
    unsigned short* x1b = cat_bf + 655360;   // 512*384
    unsigned short* h1b = x1b + 196608;      // 512*768
    unsigned short* h2b = h1b + 393216;      // 512*768
    unsigned short* Qp  = h2b + 393216;      // 512*8*32
    unsigned short* Kp  = Qp + 131072;
    unsigned short* svT = Kp + 131072;       // 8*32*512
    unsigned short* WoT = svT + 131072;      // 384*1280
    unsigned short* W1T = WoT + 491520;      // 768*384
    unsigned short* W2T = W1T + 294912;      // 768*768
    unsigned short* W3T = W2T + 589824;      // 384*768
    unsigned short* WprojT = W3T + 294912;   // 672*384
    unsigned short* nfb = WprojT + 258048;   // 512*384

    prep_weights_kernel<<<2076, 256, 0, stream>>>(Wo, W1, W2, W3,
                                                  Wq_s, Wk_s, Wv_s, Wq_p, Wk_p, Wv_p, nf,
                                                  WoT, W1T, W2T, W3T, WprojT, nfb);

    gemm_bf16<384, 672, false, false, false><<<dim3(42, 8), 256, 0, stream>>>(nfb, WprojT, nullptr, proj_out);

    ipa_post_kernel<<<NN, 256, 0, stream>>>(proj_out, rot, trans, pw, bb, Qp, Kp, svT);

    ipa_fused2<<<dim3(JSPLIT, 64), 256, 0, stream>>>(edge, Qp, Kp, svT, Wb,
                                                     Opart, Mpart, Lpart);

    ipa_merge<<<NN, 256, 0, stream>>>(Opart, Mpart, Lpart, rot, trans, cat_bf);

    gemm_bf16<1280, 384, false, true, false><<<dim3(24, 8), 256, 0, stream>>>(cat_bf, WoT, bo, ipa);
    ln_kernel<true><<<NN, 256, 0, stream>>>(ipa, g1, be1, x1b, 384);

    gemm_bf16<384, 768, true, true, true><<<dim3(48, 8), 256, 0, stream>>>(x1b, W1T, b1, h1b);
    gemm_bf16<768, 768, true, true, true><<<dim3(48, 8), 256, 0, stream>>>(h1b, W2T, b2, h2b);
    gemm_bf16<768, 384, false, true, false><<<dim3(24, 8), 256, 0, stream>>>(h2b, W3T, b3, y);

    ln_kernel<false><<<NN, 256, 0, stream>>>(y, g2, be2, d_out, 384);
}

// Round 7
// 343.937 us; speedup vs baseline: 2.4768x; 2.4768x over previous
//
#include <hip/hip_runtime.h>
#include <cstddef>

#define NN 512
#define DD 384
#define EE 128
#define HH 8
#define JSPLIT 16          // j-splits in fused attention (32 j each)

static constexpr float SCAL_SCALE  = 0.1443375673f;   // 1/sqrt(3*16)
static constexpr float POINT_SCALE = 0.1360827635f;   // 1/sqrt(3*4*4.5)
static constexpr float PAIR_SCALE  = 0.5773502692f;   // 1/sqrt(3)
static constexpr float LN_EPS = 1e-5f;
static constexpr float EPS    = 1e-8f;

typedef __bf16 bf16x8 __attribute__((ext_vector_type(8)));
typedef float  f32x4  __attribute__((ext_vector_type(4)));

__device__ __forceinline__ unsigned short bf16_bits(float v) {
    union { __bf16 b; unsigned short s; } c; c.b = (__bf16)v; return c.s;
}
__device__ __forceinline__ float bits2f(unsigned u) {
    union { unsigned u; float f; } c; c.u = u; return c.f;
}

// ---------------------------------------------------------------------------
// Unified prep: fp32 W[K][N] -> bf16 Wt[N][K] for all weights (proj combined
// into WprojT[672][384]) + straight fp32->bf16 copy of nf -> nfb.
// ---------------------------------------------------------------------------
__global__ __launch_bounds__(256) void prep_weights_kernel(
    const float* __restrict__ Wo, const float* __restrict__ W1,
    const float* __restrict__ W2, const float* __restrict__ W3,
    const float* __restrict__ Wq_s, const float* __restrict__ Wk_s,
    const float* __restrict__ Wv_s,
    const float* __restrict__ Wq_p, const float* __restrict__ Wk_p,
    const float* __restrict__ Wv_p, const float* __restrict__ nf,
    unsigned short* __restrict__ WoT, unsigned short* __restrict__ W1T,
    unsigned short* __restrict__ W2T, unsigned short* __restrict__ W3T,
    unsigned short* __restrict__ WprojT, unsigned short* __restrict__ nfb)
{
    const int b = blockIdx.x;
    if (b >= 1884) {   // nf convert: 192 blocks x 1024 elems
        const int idx = (b - 1884) * 1024 + threadIdx.x * 4;
        float4 v = *(const float4*)(nf + idx);
        unsigned lo = bf16_bits(v.x) | ((unsigned)bf16_bits(v.y) << 16);
        unsigned hi = bf16_bits(v.z) | ((unsigned)bf16_bits(v.w) << 16);
        uint2 pk; pk.x = lo; pk.y = hi;
        *(uint2*)(nfb + idx) = pk;
        return;
    }
    const float* W; unsigned short* out;
    int K, N, tile, rowoff = 0;
    if (b < 480)       { W = Wo;   out = WoT;    K = 1280; N = 384; tile = b; }
    else if (b < 768)  { W = W1;   out = W1T;    K = 384;  N = 768; tile = b - 480; }
    else if (b < 1344) { W = W2;   out = W2T;    K = 768;  N = 768; tile = b - 768; }
    else if (b < 1632) { W = W3;   out = W3T;    K = 768;  N = 384; tile = b - 1344; }
    else if (b < 1680) { W = Wq_s; out = WprojT; K = 384;  N = 128; tile = b - 1632; rowoff = 0; }
    else if (b < 1728) { W = Wk_s; out = WprojT; K = 384;  N = 128; tile = b - 1680; rowoff = 128; }
    else if (b < 1776) { W = Wv_s; out = WprojT; K = 384;  N = 128; tile = b - 1728; rowoff = 256; }
    else if (b < 1812) { W = Wq_p; out = WprojT; K = 384;  N = 96;  tile = b - 1776; rowoff = 384; }
    else if (b < 1848) { W = Wk_p; out = WprojT; K = 384;  N = 96;  tile = b - 1812; rowoff = 480; }
    else               { W = Wv_p; out = WprojT; K = 384;  N = 96;  tile = b - 1848; rowoff = 576; }

    const int ntn = N / 32;
    const int n0 = (tile % ntn) * 32, k0 = (tile / ntn) * 32;
    __shared__ float tb[32][33];
    const int tx = threadIdx.x & 31, ty = threadIdx.x >> 5;
    #pragma unroll
    for (int dy = 0; dy < 32; dy += 8)
        tb[ty + dy][tx] = W[(size_t)(k0 + ty + dy) * N + n0 + tx];
    __syncthreads();
    #pragma unroll
    for (int dy = 0; dy < 32; dy += 8)
        out[(size_t)(rowoff + n0 + ty + dy) * K + k0 + tx] = bf16_bits(tb[tx][ty + dy]);
}

// ---------------------------------------------------------------------------
// Barrier-free bf16 GEMM: Y[M,NOUT] = Xb[M,K](bf16) @ Wt[NOUT,K]^T + bias.
// Per-wave direct-global A/B fragment loads, no LDS. Block: 64m x 16n.
// grid (NOUT/16, M/64).
// ---------------------------------------------------------------------------
template <int K, int NOUT, bool RELU, bool HASB, bool OUTBF>
__global__ __launch_bounds__(256) void gemm_bf16(
    const unsigned short* __restrict__ Xb, const unsigned short* __restrict__ Wt,
    const float* __restrict__ bias, void* __restrict__ Yv)
{
    const int t = threadIdx.x;
    const int w = t >> 6, lane = t & 63;
    const int r = lane & 15, q = lane >> 4;
    const int n0 = blockIdx.x * 16;
    const int m0 = blockIdx.y * 64 + w * 16;

    const unsigned short* xrow = Xb + (size_t)(m0 + r) * K + q * 8;
    const unsigned short* wrow = Wt + (size_t)(n0 + r) * K + q * 8;

    f32x4 acc = {0.f, 0.f, 0.f, 0.f};
    #pragma unroll 4
    for (int k0 = 0; k0 < K; k0 += 32) {
        union { uint4 u; bf16x8 v; } au, bu;
        au.u = *(const uint4*)(xrow + k0);
        bu.u = *(const uint4*)(wrow + k0);
        acc = __builtin_amdgcn_mfma_f32_16x16x32_bf16(au.v, bu.v, acc, 0, 0, 0);
    }
    const int n = n0 + r;
    const float bi = HASB ? bias[n] : 0.f;
    #pragma unroll
    for (int reg = 0; reg < 4; reg++) {
        const int m = m0 + q * 4 + reg;
        float v = acc[reg] + bi;
        if (RELU) v = fmaxf(v, 0.f);
        if (OUTBF) ((unsigned short*)Yv)[(size_t)m * NOUT + n] = bf16_bits(v);
        else       ((float*)Yv)[(size_t)m * NOUT + n] = v;
    }
}

// ---------------------------------------------------------------------------
// Post-projection: rigid transform + pack Q'/K'/svT from proj_out[i][672].
// ---------------------------------------------------------------------------
__global__ __launch_bounds__(256) void ipa_post_kernel(
    const float* __restrict__ proj_out, const float* __restrict__ rot,
    const float* __restrict__ trans, const float* __restrict__ pw,
    const float* __restrict__ bb,
    unsigned short* __restrict__ Qp, unsigned short* __restrict__ Kp,
    unsigned short* __restrict__ svT)
{
    const int i = blockIdx.x;
    const int t = threadIdx.x;
    __shared__ float outs[672];
    __shared__ float ptg[288];
    __shared__ float q2s[8], k2s[8], pwh[8];

    for (int f = t; f < 672; f += 256) outs[f] = proj_out[(size_t)i * 672 + f];
    if (t < 8) pwh[t] = 0.5f * POINT_SCALE * log1pf(expf(pw[t]));
    __syncthreads();

    for (int f = t; f < 288; f += 256) {
        int which = f / 96, idx = f % 96;
        int hd = idx / 3, r = idx % 3;
        float acc = trans[(size_t)i * 3 + r];
        #pragma unroll
        for (int c = 0; c < 3; c++)
            acc += outs[384 + which * 96 + hd * 3 + c] * rot[(size_t)i * 9 + c * 3 + r];
        ptg[f] = acc;
    }
    __syncthreads();
    if (t < 16) {
        int which = t / 8, h = t % 8;
        float acc = 0.f;
        #pragma unroll
        for (int m = 0; m < 12; m++) {
            float v = ptg[which * 96 + h * 12 + m];
            acc += v * v;
        }
        (which ? k2s : q2s)[h] = acc;
    }
    __syncthreads();

    {
        const int h = t >> 5, d = t & 31;
        float qv, kv;
        if (d < 16)      { qv = outs[h * 16 + d] * SCAL_SCALE; kv = outs[128 + h * 16 + d]; }
        else if (d < 28) { qv = ptg[h * 12 + d - 16] * (2.f * pwh[h]); kv = ptg[96 + h * 12 + d - 16]; }
        else if (d == 28){ qv = -pwh[h] * q2s[h]; kv = 1.f; }
        else if (d == 29){ qv = 1.f; kv = -pwh[h] * k2s[h]; }
        else if (d == 30){ qv = 1.f; kv = bb[h] * PAIR_SCALE; }
        else             { qv = 0.f; kv = 0.f; }
        Qp[((size_t)i * 8 + h) * 32 + d] = bf16_bits(qv);
        Kp[((size_t)i * 8 + h) * 32 + d] = bf16_bits(kv);
    }
    if (t < 128) {
        int h = t >> 4, v = t & 15;
        svT[((size_t)h * 32 + v) * NN + i] = bf16_bits(outs[256 + h * 16 + v]);
    } else if (t < 224) {
        int idx = t - 128, h = idx / 12, m = idx % 12;
        svT[((size_t)h * 32 + 16 + m) * NN + i] = bf16_bits(ptg[192 + idx]);
    }
}

// ---------------------------------------------------------------------------
// FUSED flash-IPA v2 (spill-fixed: NO forced occupancy bound — large
// per-thread accumulator state needs ~160 VGPRs; R6's (256,3) bound forced
// 84 VGPRs -> 1.6 GB scratch spill traffic).
// Block: 8 i-rows x 32 j (4 subtiles of 8 j). grid (16 j-splits, 64 i-tiles).
// ---------------------------------------------------------------------------
__global__ __launch_bounds__(256) void ipa_fused2(
    const float* __restrict__ edge,
    const unsigned short* __restrict__ Qp, const unsigned short* __restrict__ Kp,
    const unsigned short* __restrict__ svT, const float* __restrict__ Wb,
    float* __restrict__ Opart, float* __restrict__ Mpart, float* __restrict__ Lpart)
{
    const int js = blockIdx.x;           // 0..15
    const int it = blockIdx.y;           // 0..63
    const int i0 = it * 8;
    const int jbase = js * 32;
    const int t = threadIdx.x;
    const int w = t >> 6, lane = t & 63;
    const int r = lane & 15, q = lane >> 4;

    __shared__ unsigned short wbT[16 * 128];   // [h(16)][e] *PAIR_SCALE
    __shared__ unsigned short edA[64 * 128];   // [row=jl*8+il][e] chunk^(row&15)
    __shared__ float Lqk[64 * 37];             // [(h*8+i)][j(32) pad37]
    __shared__ float Lb[64 * 9];               // [(h*8+i)][j(8) pad9]
    __shared__ unsigned short svj[8 * 8 * 32]; // [h][j][c pad32]
    __shared__ float mrow[64], lrow[64], arow[64];

    for (int idx = t; idx < 2048; idx += 256) {
        int h = idx >> 7, e = idx & 127;
        wbT[idx] = bf16_bits((h < 8) ? Wb[e * 8 + h] * PAIR_SCALE : 0.f);
    }
    if (t < 64) { mrow[t] = -1e30f; lrow[t] = 0.f; }
    __syncthreads();

    bf16x8 wbf[4];
    #pragma unroll
    for (int s = 0; s < 4; s++)
        wbf[s] = *(const bf16x8*)&wbT[r * 128 + s * 32 + q * 8];

    // qk logits for the whole 32-j strip, once: wave w owns h = 2w, 2w+1
    #pragma unroll
    for (int hh = 0; hh < 2; hh++) {
        const int h = w * 2 + hh;
        bf16x8 aq = *(const bf16x8*)&Qp[((size_t)(i0 + (r & 7)) * 8 + h) * 32 + q * 8];
        #pragma unroll
        for (int jt = 0; jt < 2; jt++) {
            bf16x8 bk = *(const bf16x8*)&Kp[((size_t)(jbase + jt * 16 + r) * 8 + h) * 32 + q * 8];
            f32x4 acc = {0.f, 0.f, 0.f, 0.f};
            acc = __builtin_amdgcn_mfma_f32_16x16x32_bf16(aq, bk, acc, 0, 0, 0);
            if (q < 2) {
                #pragma unroll
                for (int reg = 0; reg < 4; reg++)
                    Lqk[(h * 8 + q * 4 + reg) * 37 + jt * 16 + r] = acc[reg];
            }
        }
    }

    // prefetch machinery
    const int sj = t >> 5, sih = (t >> 4) & 1, sseg = t & 15;
    const int hsv = t / 28, csv = t % 28;    // valid t<224
    float4 pf[8];
    uint4 svpf;
    {
        const int j0 = jbase;
        #pragma unroll
        for (int il = 0; il < 4; il++) {
            const float* src = edge + (((size_t)(i0 + sih * 4 + il) * NN) + (j0 + sj)) * EE + sseg * 8;
            pf[il * 2]     = *(const float4*)src;
            pf[il * 2 + 1] = *(const float4*)(src + 4);
        }
        if (t < 224) svpf = *(const uint4*)&svT[(size_t)(hsv * 32 + csv) * NN + j0];
    }

    // accumulators: thread = (i = t>>5, h = (t>>2)&7, part = t&3)
    const int ai = t >> 5, ah = (t >> 2) & 7, ap = t & 3;
    const int prow = ah * 8 + ai;
    float rp[32];
    float sva[8];
    #pragma unroll
    for (int z = 0; z < 32; z++) rp[z] = 0.f;
    #pragma unroll
    for (int s = 0; s < 8; s++) sva[s] = 0.f;

    for (int st = 0; st < 4; st++) {
        __syncthreads();   // edA/svj free
        // commit prefetched tile to LDS
        #pragma unroll
        for (int il = 0; il < 4; il++) {
            const int row = sj * 8 + sih * 4 + il;
            union { bf16x8 v; uint4 u; } pk;
            pk.v[0] = (__bf16)pf[il*2].x;   pk.v[1] = (__bf16)pf[il*2].y;
            pk.v[2] = (__bf16)pf[il*2].z;   pk.v[3] = (__bf16)pf[il*2].w;
            pk.v[4] = (__bf16)pf[il*2+1].x; pk.v[5] = (__bf16)pf[il*2+1].y;
            pk.v[6] = (__bf16)pf[il*2+1].z; pk.v[7] = (__bf16)pf[il*2+1].w;
            *(uint4*)&edA[row * 128 + ((sseg ^ (row & 15)) * 8)] = pk.u;
        }
        if (t < 224) {
            svj[(hsv * 8 + 0) * 32 + csv] = (unsigned short)(svpf.x & 0xffff);
            svj[(hsv * 8 + 1) * 32 + csv] = (unsigned short)(svpf.x >> 16);
            svj[(hsv * 8 + 2) * 32 + csv] = (unsigned short)(svpf.y & 0xffff);
            svj[(hsv * 8 + 3) * 32 + csv] = (unsigned short)(svpf.y >> 16);
            svj[(hsv * 8 + 4) * 32 + csv] = (unsigned short)(svpf.z & 0xffff);
            svj[(hsv * 8 + 5) * 32 + csv] = (unsigned short)(svpf.z >> 16);
            svj[(hsv * 8 + 6) * 32 + csv] = (unsigned short)(svpf.w & 0xffff);
            svj[(hsv * 8 + 7) * 32 + csv] = (unsigned short)(svpf.w >> 16);
        }
        // issue next prefetch (overlaps MFMA + softmax + accumulate)
        if (st < 3) {
            const int j0 = jbase + (st + 1) * 8;
            #pragma unroll
            for (int il = 0; il < 4; il++) {
                const float* src = edge + (((size_t)(i0 + sih * 4 + il) * NN) + (j0 + sj)) * EE + sseg * 8;
                pf[il * 2]     = *(const float4*)src;
                pf[il * 2 + 1] = *(const float4*)(src + 4);
            }
            if (t < 224) svpf = *(const uint4*)&svT[(size_t)(hsv * 32 + csv) * NN + j0];
        }
        __syncthreads();

        // pair-bias MFMA: wave w covers rows w*16..w*16+15 = (jl,il) pairs
        {
            f32x4 acc = {0.f, 0.f, 0.f, 0.f};
            #pragma unroll
            for (int s = 0; s < 4; s++) {
                bf16x8 a = *(const bf16x8*)&edA[(w * 16 + r) * 128 + (((s * 4 + q) ^ r) * 8)];
                acc = __builtin_amdgcn_mfma_f32_16x16x32_bf16(a, wbf[s], acc, 0, 0, 0);
            }
            if (r < 8) {   // col r = h; row m = q*4+reg -> jl = w*2+(m>>3), il = m&7
                #pragma unroll
                for (int reg = 0; reg < 4; reg++) {
                    const int m = q * 4 + reg;
                    Lb[(r * 8 + (m & 7)) * 9 + (w * 2 + (m >> 3))] = acc[reg];
                }
            }
        }
        __syncthreads();

        // online softmax: t<64 owns (h = t>>3, i = t&7)
        if (t < 64) {
            float lg[8];
            float mx = -1e30f;
            #pragma unroll
            for (int j = 0; j < 8; j++) {
                lg[j] = Lb[t * 9 + j] + Lqk[t * 37 + st * 8 + j];
                mx = fmaxf(mx, lg[j]);
            }
            const float mnew = fmaxf(mrow[t], mx);
            const float al = __expf(mrow[t] - mnew);
            float sum = 0.f;
            #pragma unroll
            for (int j = 0; j < 8; j++) {
                float p = __expf(lg[j] - mnew);
                Lb[t * 9 + j] = p;
                sum += p;
            }
            lrow[t] = lrow[t] * al + sum;
            mrow[t] = mnew;
            arow[t] = al;
        }
        __syncthreads();

        // accumulate
        const float al = arow[prow];
        float pj[8];
        #pragma unroll
        for (int j = 0; j < 8; j++) pj[j] = Lb[prow * 9 + j];
        #pragma unroll
        for (int z = 0; z < 32; z++) rp[z] *= al;
        #pragma unroll
        for (int s = 0; s < 8; s++) sva[s] *= al;

        #pragma unroll
        for (int j = 0; j < 8; j++) {
            const int row = j * 8 + ai;
            const float p = pj[j];
            #pragma unroll
            for (int u = 0; u < 4; u++) {
                uint4 ev = *(const uint4*)&edA[row * 128 + (((ap * 4 + u) ^ (row & 15)) * 8)];
                rp[u*8+0] += p * bits2f(ev.x << 16);
                rp[u*8+1] += p * bits2f(ev.x & 0xffff0000u);
                rp[u*8+2] += p * bits2f(ev.y << 16);
                rp[u*8+3] += p * bits2f(ev.y & 0xffff0000u);
                rp[u*8+4] += p * bits2f(ev.z << 16);
                rp[u*8+5] += p * bits2f(ev.z & 0xffff0000u);
                rp[u*8+6] += p * bits2f(ev.w << 16);
                rp[u*8+7] += p * bits2f(ev.w & 0xffff0000u);
            }
            uint4 sv = *(const uint4*)&svj[(ah * 8 + j) * 32 + ap * 8];
            sva[0] += p * bits2f(sv.x << 16);
            sva[1] += p * bits2f(sv.x & 0xffff0000u);
            sva[2] += p * bits2f(sv.y << 16);
            sva[3] += p * bits2f(sv.y & 0xffff0000u);
            sva[4] += p * bits2f(sv.z << 16);
            sva[5] += p * bits2f(sv.z & 0xffff0000u);
            sva[6] += p * bits2f(sv.w << 16);
            sva[7] += p * bits2f(sv.w & 0xffff0000u);
        }
    }

    // writeout partials (all float4-aligned)
    float* orow = Opart + (size_t)((js * 64 + it) * 8 + ai) * 1248;
    #pragma unroll
    for (int u = 0; u < 8; u++) {
        f32x4 vv = {rp[u*4+0], rp[u*4+1], rp[u*4+2], rp[u*4+3]};
        *(f32x4*)&orow[ah * 156 + 28 + ap * 32 + u * 4] = vv;
    }
    {
        f32x4 v0 = {sva[0], sva[1], sva[2], sva[3]};
        if (ap < 3) {
            f32x4 v1 = {sva[4], sva[5], sva[6], sva[7]};
            *(f32x4*)&orow[ah * 156 + ap * 8]     = v0;
            *(f32x4*)&orow[ah * 156 + ap * 8 + 4] = v1;
        } else {
            *(f32x4*)&orow[ah * 156 + 24] = v0;   // c 24..27
        }
    }
    if (t < 64) {
        Mpart[(size_t)(js * 64 + it) * 64 + t] = mrow[t];
        Lpart[(size_t)(js * 64 + it) * 64 + t] = lrow[t];
    }
}

// ---------------------------------------------------------------------------
// Merge partials + local frame + norms -> bf16 cat row
// [rs(128) | local(96) | norms(32) | rp(1024)]. grid 512.
// ---------------------------------------------------------------------------
__global__ __launch_bounds__(256) void ipa_merge(
    const float* __restrict__ Opart, const float* __restrict__ Mpart,
    const float* __restrict__ Lpart, const float* __restrict__ rot,
    const float* __restrict__ trans, unsigned short* __restrict__ cat_bf)
{
    const int i = blockIdx.x;
    const int itile = i >> 3, il = i & 7;
    const int t = threadIdx.x;
    __shared__ float wn[8 * JSPLIT];
    __shared__ float pts_s[96];

    if (t < 8) {
        const int h = t;
        float ms[JSPLIT], ls[JSPLIT], M = -1e30f;
        #pragma unroll
        for (int s = 0; s < JSPLIT; s++) {
            ms[s] = Mpart[(size_t)(s * 64 + itile) * 64 + h * 8 + il];
            ls[s] = Lpart[(size_t)(s * 64 + itile) * 64 + h * 8 + il];
            M = fmaxf(M, ms[s]);
        }
        float denom = 0.f, e[JSPLIT];
        #pragma unroll
        for (int s = 0; s < JSPLIT; s++) { e[s] = __expf(ms[s] - M); denom += e[s] * ls[s]; }
        const float inv = 1.f / denom;
        #pragma unroll
        for (int s = 0; s < JSPLIT; s++) wn[h * JSPLIT + s] = e[s] * inv;
    }
    __syncthreads();

    for (int col = t; col < 1248; col += 256) {
        const int h = col / 156, c = col % 156;
        float acc = 0.f;
        #pragma unroll
        for (int s = 0; s < JSPLIT; s++)
            acc += wn[h * JSPLIT + s] *
                   Opart[((size_t)(s * 64 + itile) * 8 + il) * 1248 + col];
        if (c < 16)      cat_bf[(size_t)i * 1280 + h * 16 + c] = bf16_bits(acc);
        else if (c < 28) pts_s[h * 12 + (c - 16)] = acc;
        else             cat_bf[(size_t)i * 1280 + 256 + h * 128 + (c - 28)] = bf16_bits(acc);
    }
    __syncthreads();

    const float* tr = trans + (size_t)i * 3;
    const float* R  = rot + (size_t)i * 9;
    if (t < 96) {
        int hd = t / 3, rr = t % 3;
        float acc = 0.f;
        #pragma unroll
        for (int c = 0; c < 3; c++)
            acc += (pts_s[hd * 3 + c] - tr[c]) * R[rr * 3 + c];
        cat_bf[(size_t)i * 1280 + 128 + t] = bf16_bits(acc);
    } else if (t < 128) {
        int pv = t - 96;
        float s = EPS;
        #pragma unroll
        for (int rr = 0; rr < 3; rr++) {
            float v = 0.f;
            #pragma unroll
            for (int c = 0; c < 3; c++)
                v += (pts_s[pv * 3 + c] - tr[c]) * R[rr * 3 + c];
            s += v * v;
        }
        cat_bf[(size_t)i * 1280 + 224 + pv] = bf16_bits(sqrtf(s));
    }
}

// ---------------------------------------------------------------------------
// LayerNorm per row; optional bf16 output.
// ---------------------------------------------------------------------------
template <bool OUTBF>
__global__ __launch_bounds__(256) void ln_kernel(
    const float* __restrict__ X, const float* __restrict__ g,
    const float* __restrict__ beta, void* __restrict__ Yv, int Dim)
{
    __shared__ float red[4];
    __shared__ float bc;
    const int i = blockIdx.x;
    const int t = threadIdx.x;
    const float* x = X + (size_t)i * Dim;

    float s = 0.f;
    for (int k = t; k < Dim; k += 256) s += x[k];
    #pragma unroll
    for (int off = 32; off; off >>= 1) s += __shfl_down(s, off, 64);
    if ((t & 63) == 0) red[t >> 6] = s;
    __syncthreads();
    if (t == 0) bc = red[0] + red[1] + red[2] + red[3];
    __syncthreads();
    const float mu = bc / Dim;

    float v = 0.f;
    for (int k = t; k < Dim; k += 256) { float d = x[k] - mu; v += d * d; }
    #pragma unroll
    for (int off = 32; off; off >>= 1) v += __shfl_down(v, off, 64);
    __syncthreads();
    if ((t & 63) == 0) red[t >> 6] = v;
    __syncthreads();
    if (t == 0) bc = red[0] + red[1] + red[2] + red[3];
    __syncthreads();
    const float rstd = rsqrtf(bc / Dim + LN_EPS);

    for (int k = t; k < Dim; k += 256) {
        float val = (x[k] - mu) * rstd * g[k] + beta[k];
        if (OUTBF) ((unsigned short*)Yv)[(size_t)i * Dim + k] = bf16_bits(val);
        else       ((float*)Yv)[(size_t)i * Dim + k] = val;
    }
}

// ---------------------------------------------------------------------------
extern "C" void kernel_launch(void* const* d_in, const int* in_sizes, int n_in,
                              void* d_out, int out_size, void* d_ws, size_t ws_size,
                              hipStream_t stream)
{
    const float* nf    = (const float*)d_in[0];
    const float* edge  = (const float*)d_in[1];
    const float* rot   = (const float*)d_in[2];
    const float* trans = (const float*)d_in[3];
    // d_in[4] = mask — all-True, no-op
    const float* Wq_s = (const float*)d_in[5];
    const float* Wk_s = (const float*)d_in[6];
    const float* Wv_s = (const float*)d_in[7];
    const float* Wq_p = (const float*)d_in[8];
    const float* Wk_p = (const float*)d_in[9];
    const float* Wv_p = (const float*)d_in[10];
    const float* pw   = (const float*)d_in[11];
    const float* Wb   = (const float*)d_in[12];
    const float* bb   = (const float*)d_in[13];
    const float* Wo   = (const float*)d_in[14];
    const float* bo   = (const float*)d_in[15];
    const float* g1   = (const float*)d_in[16];
    const float* be1  = (const float*)d_in[17];
    const float* W1   = (const float*)d_in[18];
    const float* b1   = (const float*)d_in[19];
    const float* W2   = (const float*)d_in[20];
    const float* b2   = (const float*)d_in[21];
    const float* W3   = (const float*)d_in[22];
    const float* b3   = (const float*)d_in[23];
    const float* g2   = (const float*)d_in[24];
    const float* be2  = (const float*)d_in[25];

    float* ws = (float*)d_ws;
    float* proj_out = ws;                    // 512*672
    float* ipa   = proj_out + 344064;        // 512*384
    float* y     = ipa + 196608;             // 512*384
    float* Opart = y + 196608;               // 16*64*8 * 1248
    float* Mpart = Opart + 10223616;         // 16*64*64
    float* Lpart = Mpart + 65536;
    unsigned short* cat_bf = (unsigned short*)(Lpart + 65536); // 512*1280
    unsigned short* x1b = cat_bf + 655360;   // 512*384
    unsigned short* h1b = x1b + 196608;      // 512*768
    unsigned short* h2b = h1b + 393216;      // 512*768
    unsigned short* Qp  = h2b + 393216;      // 512*8*32
    unsigned short* Kp  = Qp + 131072;
    unsigned short* svT = Kp + 131072;       // 8*32*512
    unsigned short* WoT = svT + 131072;      // 384*1280
    unsigned short* W1T = WoT + 491520;      // 768*384
    unsigned short* W2T = W1T + 294912;      // 768*768
    unsigned short* W3T = W2T + 589824;      // 384*768
    unsigned short* WprojT = W3T + 294912;   // 672*384
    unsigned short* nfb = WprojT + 258048;   // 512*384

    prep_weights_kernel<<<2076, 256, 0, stream>>>(Wo, W1, W2, W3,
                                                  Wq_s, Wk_s, Wv_s, Wq_p, Wk_p, Wv_p, nf,
                                                  WoT, W1T, W2T, W3T, WprojT, nfb);

    gemm_bf16<384, 672, false, false, false><<<dim3(42, 8), 256, 0, stream>>>(nfb, WprojT, nullptr, proj_out);

    ipa_post_kernel<<<NN, 256, 0, stream>>>(proj_out, rot, trans, pw, bb, Qp, Kp, svT);

    ipa_fused2<<<dim3(JSPLIT, 64), 256, 0, stream>>>(edge, Qp, Kp, svT, Wb,
                                                     Opart, Mpart, Lpart);

    ipa_merge<<<NN, 256, 0, stream>>>(Opart, Mpart, Lpart, rot, trans, cat_bf);

    gemm_bf16<1280, 384, false, true, false><<<dim3(24, 8), 256, 0, stream>>>(cat_bf, WoT, bo, ipa);
    ln_kernel<true><<<NN, 256, 0, stream>>>(ipa, g1, be1, x1b, 384);

    gemm_bf16<384, 768, true, true, true><<<dim3(48, 8), 256, 0, stream>>>(x1b, W1T, b1, h1b);
    gemm_bf16<768, 768, true, true, true><<<dim3(48, 8), 256, 0, stream>>>(h1b, W2T, b2, h2b);
    gemm_bf16<768, 384, false, true, false><<<dim3(24, 8), 256, 0, stream>>>(h2b, W3T, b3, y);

    ln_kernel<false><<<NN, 256, 0, stream>>>(y, g2, be2, d_out, 384);
}